// Round 2
// baseline (453.703 us; speedup 1.0000x reference)
//
#include <hip/hip_runtime.h>
#include <math.h>

// HebbyRNN: B=32, IN=128, H=1024, OUT=128
// Chain of batched GEMVs (per-sample weight matrices) + tanh, log_softmax head.
// ~570 MB of weights, each element read exactly once -> roofline ~90us @ 6.3 TB/s.
// R3: 4 rows per wave (4x memory-level parallelism per wave, 4x fewer waves),
//     butterfly reduce + lanes 0..3 parallel epilogue, nontemporal W loads.
// 5 dispatches total. (Resubmitted unchanged after two infra-level bench failures.)

#define B_SZ 32
#define IN_SZ 128
#define H_SZ 1024
#define OUT_SZ 128

typedef float f4 __attribute__((ext_vector_type(4)));

__device__ __forceinline__ float dot4(f4 w, f4 a, float acc) {
    acc = fmaf(w.x, a.x, acc);
    acc = fmaf(w.y, a.y, acc);
    acc = fmaf(w.z, a.z, acc);
    acc = fmaf(w.w, a.w, acc);
    return acc;
}

// Full 64-lane butterfly: every lane ends with the total.
__device__ __forceinline__ float wave_allreduce(float s) {
    #pragma unroll
    for (int off = 32; off > 0; off >>= 1)
        s += __shfl_xor(s, off, 64);
    return s;
}

// Layer 0: W0 [B,1024,1152] * concat(x,hidden) -> tanh -> out [B,1024]
// 4 rows per wave; row = 288 float4; lanes cover 4 full strides + lanes<32 a 5th.
__global__ __launch_bounds__(256) void gemv0_kernel(
        const float* __restrict__ W, const float* __restrict__ bias,
        const float* __restrict__ x, const float* __restrict__ h,
        float* __restrict__ out) {
    int wave = blockIdx.x * 4 + (threadIdx.x >> 6);   // 0..8191
    int lane = threadIdx.x & 63;
    int r0 = wave << 2;                               // base row (4 rows/wave)
    int b = r0 >> 10;

    const f4* __restrict__ x4 = (const f4*)(x + b * IN_SZ);   // 32 f4
    const f4* __restrict__ h4 = (const f4*)(h + b * H_SZ);    // 256 f4

    // activation fragment, loaded once, reused for all 4 rows
    f4 a[4];
    #pragma unroll
    for (int k = 0; k < 4; k++) {
        int j = lane + 64 * k;
        a[k] = (j < 32) ? x4[j] : h4[j - 32];
    }
    f4 a4;
    if (lane < 32) a4 = h4[224 + lane];

    float s0 = 0.f, s1 = 0.f, s2 = 0.f, s3 = 0.f;
    #pragma unroll
    for (int r = 0; r < 4; r++) {
        const f4* __restrict__ Wr = (const f4*)(W + (size_t)(r0 + r) * (IN_SZ + H_SZ));
        float s = 0.f;
        #pragma unroll
        for (int k = 0; k < 4; k++)
            s = dot4(__builtin_nontemporal_load(Wr + lane + 64 * k), a[k], s);
        if (lane < 32)
            s = dot4(__builtin_nontemporal_load(Wr + 256 + lane), a4, s);
        if      (r == 0) s0 = s;
        else if (r == 1) s1 = s;
        else if (r == 2) s2 = s;
        else             s3 = s;
    }
    s0 = wave_allreduce(s0);
    s1 = wave_allreduce(s1);
    s2 = wave_allreduce(s2);
    s3 = wave_allreduce(s3);
    if (lane < 4) {
        float v = (lane == 0) ? s0 : (lane == 1) ? s1 : (lane == 2) ? s2 : s3;
        int o = (r0 & (H_SZ - 1)) + lane;
        out[r0 + lane] = tanhf(v + bias[o]);
    }
}

// Middle layers: W [B,1024,1024] * v -> tanh. 4 rows per wave, row = 256 f4.
__global__ __launch_bounds__(256) void gemv_mid_kernel(
        const float* __restrict__ W, const float* __restrict__ bias,
        const float* __restrict__ v, float* __restrict__ out) {
    int wave = blockIdx.x * 4 + (threadIdx.x >> 6);   // 0..8191
    int lane = threadIdx.x & 63;
    int r0 = wave << 2;
    int b = r0 >> 10;

    const f4* __restrict__ vr = (const f4*)(v + b * H_SZ);
    f4 a[4];
    #pragma unroll
    for (int k = 0; k < 4; k++) a[k] = vr[lane + 64 * k];

    float s0 = 0.f, s1 = 0.f, s2 = 0.f, s3 = 0.f;
    #pragma unroll
    for (int r = 0; r < 4; r++) {
        const f4* __restrict__ Wr = (const f4*)(W + (size_t)(r0 + r) * H_SZ);
        float s = 0.f;
        #pragma unroll
        for (int k = 0; k < 4; k++)
            s = dot4(__builtin_nontemporal_load(Wr + lane + 64 * k), a[k], s);
        if      (r == 0) s0 = s;
        else if (r == 1) s1 = s;
        else if (r == 2) s2 = s;
        else             s3 = s;
    }
    s0 = wave_allreduce(s0);
    s1 = wave_allreduce(s1);
    s2 = wave_allreduce(s2);
    s3 = wave_allreduce(s3);
    if (lane < 4) {
        float v2 = (lane == 0) ? s0 : (lane == 1) ? s1 : (lane == 2) ? s2 : s3;
        int o = (r0 & (H_SZ - 1)) + lane;
        out[r0 + lane] = tanhf(v2 + bias[o]);
    }
}

// Fused heads: rows [0,32768) -> Wh (tanh -> new_hidden), [32768,36864) -> Wo (logits).
__global__ __launch_bounds__(256) void heads_kernel(
        const float* __restrict__ Wh, const float* __restrict__ bh,
        const float* __restrict__ Wo, const float* __restrict__ bo,
        const float* __restrict__ v,
        float* __restrict__ new_hidden, float* __restrict__ logits) {
    int wave = blockIdx.x * 4 + (threadIdx.x >> 6);   // 0..9215
    int lane = threadIdx.x & 63;
    int r0 = wave << 2;
    bool isO = r0 >= B_SZ * H_SZ;                     // wave-uniform (4 | 32768)
    int rr = isO ? r0 - B_SZ * H_SZ : r0;
    int b = isO ? (rr >> 7) : (rr >> 10);

    const float* Wbase = isO ? (Wo + (size_t)rr * H_SZ) : (Wh + (size_t)rr * H_SZ);
    const f4* __restrict__ vr = (const f4*)(v + b * H_SZ);
    f4 a[4];
    #pragma unroll
    for (int k = 0; k < 4; k++) a[k] = vr[lane + 64 * k];

    float s0 = 0.f, s1 = 0.f, s2 = 0.f, s3 = 0.f;
    #pragma unroll
    for (int r = 0; r < 4; r++) {
        const f4* __restrict__ Wr = (const f4*)(Wbase + (size_t)r * H_SZ);
        float s = 0.f;
        #pragma unroll
        for (int k = 0; k < 4; k++)
            s = dot4(__builtin_nontemporal_load(Wr + lane + 64 * k), a[k], s);
        if      (r == 0) s0 = s;
        else if (r == 1) s1 = s;
        else if (r == 2) s2 = s;
        else             s3 = s;
    }
    s0 = wave_allreduce(s0);
    s1 = wave_allreduce(s1);
    s2 = wave_allreduce(s2);
    s3 = wave_allreduce(s3);
    if (lane < 4) {
        float s = (lane == 0) ? s0 : (lane == 1) ? s1 : (lane == 2) ? s2 : s3;
        if (isO) {
            int o = (rr & (OUT_SZ - 1)) + lane;
            logits[rr + lane] = s + bo[o];
        } else {
            int o = (rr & (H_SZ - 1)) + lane;
            new_hidden[rr + lane] = tanhf(s + bh[o]);
        }
    }
}

// log_softmax over OUT=128 logits, one wave per batch row (2 logits/lane)
__global__ void logsoftmax_kernel(const float* __restrict__ logits,
                                  float* __restrict__ out) {
    int b = blockIdx.x;          // 32 blocks x 64 threads
    int lane = threadIdx.x;
    float v0 = logits[b * OUT_SZ + lane];
    float v1 = logits[b * OUT_SZ + 64 + lane];
    float m = fmaxf(v0, v1);
    #pragma unroll
    for (int off = 32; off > 0; off >>= 1)
        m = fmaxf(m, __shfl_xor(m, off, 64));
    float e = __expf(v0 - m) + __expf(v1 - m);
    #pragma unroll
    for (int off = 32; off > 0; off >>= 1)
        e += __shfl_xor(e, off, 64);
    float lse = m + logf(e);
    out[b * OUT_SZ + lane]      = v0 - lse;
    out[b * OUT_SZ + 64 + lane] = v1 - lse;
}

extern "C" void kernel_launch(void* const* d_in, const int* in_sizes, int n_in,
                              void* d_out, int out_size, void* d_ws, size_t ws_size,
                              hipStream_t stream) {
    const float* x      = (const float*)d_in[0];
    const float* hidden = (const float*)d_in[1];
    const float* W0 = (const float*)d_in[2];
    const float* b0 = (const float*)d_in[3];
    const float* W1 = (const float*)d_in[4];
    const float* b1 = (const float*)d_in[5];
    const float* W2 = (const float*)d_in[6];
    const float* b2 = (const float*)d_in[7];
    const float* Wh = (const float*)d_in[8];
    const float* bh = (const float*)d_in[9];
    const float* Wo = (const float*)d_in[10];
    const float* bo = (const float*)d_in[11];

    float* out_ls     = (float*)d_out;              // [32,128] log_softmax
    float* new_hidden = out_ls + B_SZ * OUT_SZ;     // [32,1024]

    float* ws = (float*)d_ws;
    float* c1 = ws;                                  // 32*1024
    float* c2 = c1 + B_SZ * H_SZ;                    // 32*1024
    float* logits = c2 + B_SZ * H_SZ;                // 32*128

    // 4 rows/wave, 4 waves/block -> 16 rows/block
    const int blocksH = (B_SZ * H_SZ) / 16;          // 2048 blocks of 256
    gemv0_kernel<<<blocksH, 256, 0, stream>>>(W0, b0, x, hidden, c1);
    gemv_mid_kernel<<<blocksH, 256, 0, stream>>>(W1, b1, c1, c2);
    gemv_mid_kernel<<<blocksH, 256, 0, stream>>>(W2, b2, c2, c1);

    const int blocksHeads = (B_SZ * H_SZ + B_SZ * OUT_SZ) / 16;  // 2304
    heads_kernel<<<blocksHeads, 256, 0, stream>>>(Wh, bh, Wo, bo, c1, new_hidden, logits);

    logsoftmax_kernel<<<B_SZ, 64, 0, stream>>>(logits, out_ls);
}